// Round 1
// baseline (272.216 us; speedup 1.0000x reference)
//
#include <hip/hip_runtime.h>

// SNN model, analyzed:
//  - mem_fict (syn_w matmuls, tau decay) is dead state -> skipped entirely.
//  - mem_phys is uniform across neurons -> 4-bit per-batch states s0,s1.
//  - d0[j,v] = ALPHA*(v-mem_map0[j,v]) * C0[v]  (C = visit counts of state v).
//  - Only real work: XOR-reduce of frames (151.5 MB). HBM/L3-bound.
//  NOTES: cooperative fusion regressed 264->492; done-counter fold regressed
//  264->786. This round: cached (non-NT) frame loads to test LLC residency
//  (frames 151.5MB < 256MB LLC); accany in [b][t] layout so kernel B's scan
//  reads 1 dword per 4 timesteps (conflict-free, stride-33 banks) and has[]
//  masks are built in-register during staging (no second LDS pass).
//
// ws layout: accany[BT] bytes ([b][t]), tabs[32] ints.

#define ALPHA_F 0.001f

typedef int iv4 __attribute__((ext_vector_type(4)));   // native vector loads

// ---------- Kernel A: one wave per (b,t) XOR-reduce; last block builds LUTs ----------
__global__ __launch_bounds__(256) void frames_reduce_kernel(
    const iv4* __restrict__ frames4, unsigned char* __restrict__ accany,
    int* __restrict__ tabs,
    const float* __restrict__ v_th0, const int* __restrict__ neuron_id0,
    const float* __restrict__ mem_map0,
    const float* __restrict__ v_th1, const float* __restrict__ mem_map1,
    int n4, int n_hid, int n_out, int nblocks, int B, int T) {
  int tid = threadIdx.x;
  int wv = tid >> 6, lane = tid & 63;

  if ((int)blockIdx.x < nblocks) {
    // Streaming path: wave wv handles bt = blockIdx*4 + wv independently.
    int bt = blockIdx.x * 4 + wv;
    const iv4* fp = frames4 + (size_t)bt * n4;
    int i0 = (lane << 2) & 15;     // loop-invariant: (4*(lane+64k)) & 15
    int x = 0, anyv = 0;
#pragma unroll 5
    for (int idx = lane; idx < n4; idx += 64) {
      iv4 f = fp[idx];             // cached load: frames may stay LLC-resident
      if (f.x > 0) { x ^= i0;       anyv = 1; }
      if (f.y > 0) { x ^= (i0 + 1); anyv = 1; }
      if (f.z > 0) { x ^= (i0 + 2); anyv = 1; }
      if (f.w > 0) { x ^= (i0 + 3); anyv = 1; }
    }
#pragma unroll
    for (int off = 32; off > 0; off >>= 1) {
      x ^= __shfl_xor(x, off);
      anyv |= __shfl_xor(anyv, off);
    }
    if (lane == 0) accany[bt] = (unsigned char)((x & 15) | (anyv << 4));
    return;
  }

  // Table block: A1[v] = XOR_j (mem_map0[j,v]>=v_th0[j] ? nid[j] : 0); spike LUT.
  int part[16];
#pragma unroll
  for (int v = 0; v < 16; v++) part[v] = 0;
  for (int j = tid; j < n_hid; j += 256) {
    float vth = v_th0[j];
    int nid = neuron_id0[j];
    const float4* mm = (const float4*)(mem_map0 + (size_t)j * 16);
    float4 m0 = mm[0], m1 = mm[1], m2 = mm[2], m3 = mm[3];
    if (m0.x >= vth) part[0]  ^= nid;
    if (m0.y >= vth) part[1]  ^= nid;
    if (m0.z >= vth) part[2]  ^= nid;
    if (m0.w >= vth) part[3]  ^= nid;
    if (m1.x >= vth) part[4]  ^= nid;
    if (m1.y >= vth) part[5]  ^= nid;
    if (m1.z >= vth) part[6]  ^= nid;
    if (m1.w >= vth) part[7]  ^= nid;
    if (m2.x >= vth) part[8]  ^= nid;
    if (m2.y >= vth) part[9]  ^= nid;
    if (m2.z >= vth) part[10] ^= nid;
    if (m2.w >= vth) part[11] ^= nid;
    if (m3.x >= vth) part[12] ^= nid;
    if (m3.y >= vth) part[13] ^= nid;
    if (m3.z >= vth) part[14] ^= nid;
    if (m3.w >= vth) part[15] ^= nid;
  }
  __shared__ int sred[4][16];
#pragma unroll
  for (int v = 0; v < 16; v++) {
    int xv = part[v];
#pragma unroll
    for (int off = 32; off > 0; off >>= 1) xv ^= __shfl_xor(xv, off);
    if (lane == 0) sred[wv][v] = xv;
  }
  __syncthreads();
  if (tid < 16) {
    tabs[tid] = (sred[0][tid] ^ sred[1][tid] ^ sred[2][tid] ^ sred[3][tid]) & 15;
    int msk = 0;
    for (int k = 0; k < n_out; k++)
      if (mem_map1[k * 16 + tid] >= v_th1[k]) msk |= (1 << k);
    tabs[16 + tid] = msk;
  }
}

// ---------- Kernel B: redundant per-block scan + grid-stride output write ----------
__global__ __launch_bounds__(256) void scan_output_kernel(
    const unsigned char* __restrict__ accany, const int* __restrict__ tabs,
    const float* __restrict__ mem_map0, const float* __restrict__ mem_map1,
    float* __restrict__ out, int B, int T, int n_hid, int n_out) {
  int tid = threadIdx.x;
  int wv = tid >> 6, lane = tid & 63;

  __shared__ unsigned char accL[128 * 132];   // [b][t], row stride 132 B
  __shared__ unsigned short smL[128 * 132];   // [t][b] spike masks
  __shared__ int sTab[32];
  __shared__ unsigned long long sAnyW[4][2];
  __shared__ int sredc0[4][16], sredc1[4][16];
  __shared__ int sCnt[32];

  // Load accany (16 KB, L2-broadcast across blocks) -> padded LDS [b][t],
  // building per-thread partial has[] masks in the same pass.
  const int* g4 = (const int*)accany;
  int nd = (B * T) >> 2;                       // 4096 dwords, 32 per b-row
  unsigned long long any01 = 0, any23 = 0;     // bit t = OR_b any(b,t)
  for (int i = tid; i < nd; i += 256) {
    unsigned int w = (unsigned int)g4[i];
    int b = i >> 5, k = i & 31;                // dword k of row b: t = 4k..4k+3
    *(unsigned int*)&accL[b * 132 + (k << 2)] = w;
    unsigned int nib = (w >> 4) & 0x01010101u;                 // any-bits of 4 bytes
    unsigned int bits4 = (nib & 1u) | ((nib >> 7) & 2u) |
                         ((nib >> 14) & 4u) | ((nib >> 21) & 8u);
    unsigned long long sh = (unsigned long long)bits4 << ((k & 15) << 2);
    if (k < 16) any01 |= sh; else any23 |= sh; // uniform-free cndmask select
  }
  if (tid < 32) sTab[tid] = tabs[tid];

  // OR-reduce the has[] masks across the wave, then across waves via LDS.
#pragma unroll
  for (int off = 32; off > 0; off >>= 1) {
    any01 |= __shfl_xor(any01, off);
    any23 |= __shfl_xor(any23, off);
  }
  if (lane == 0) { sAnyW[wv][0] = any01; sAnyW[wv][1] = any23; }
  __syncthreads();
  unsigned long long Hp0 = sAnyW[0][0] | sAnyW[1][0] | sAnyW[2][0] | sAnyW[3][0];
  unsigned long long Hp1 = sAnyW[0][1] | sAnyW[1][1] | sAnyW[2][1] | sAnyW[3][1];

  // Register LUTs: A1 as 16x4b in one u64; spike masks as 16x16b in four u64.
  unsigned long long A1p = 0, P0 = 0, P1 = 0, P2 = 0, P3 = 0;
#pragma unroll
  for (int v = 0; v < 16; v++)
    A1p |= (unsigned long long)(sTab[v] & 15) << (v * 4);
#pragma unroll
  for (int v = 0; v < 4; v++) {
    P0 |= (unsigned long long)(sTab[16 + v] & 0xFFFF) << (v * 16);
    P1 |= (unsigned long long)(sTab[20 + v] & 0xFFFF) << (v * 16);
    P2 |= (unsigned long long)(sTab[24 + v] & 0xFFFF) << (v * 16);
    P3 |= (unsigned long long)(sTab[28 + v] & 0xFFFF) << (v * 16);
  }

  // Sequential scan: thread tid = batch b (redundant per block, parallel across
  // CUs). Row bytes come from accL[b][*]: one conflict-free ds_read_b32 per 4 t.
  int myc0[16], myc1[16];
#pragma unroll
  for (int v = 0; v < 16; v++) { myc0[v] = 0; myc1[v] = 0; }

  if (tid < B) {
    int s0 = 0, s1 = 0, tlast = 0;
    unsigned long long c0lo = 0, c0hi = 0, c1lo = 0, c1hi = 0;
    const unsigned char* rowp = &accL[tid * 132];
    for (int t4 = 0; t4 < 32; t4++) {
      unsigned int quad = *(const unsigned int*)&rowp[t4 << 2];
      unsigned int hp4 = (unsigned int)(((t4 < 16 ? (Hp0 >> ((t4 & 15) << 2))
                                                  : (Hp1 >> ((t4 & 15) << 2)))) & 15ULL);
#pragma unroll
      for (int j = 0; j < 4; j++) {
        int t = (t4 << 2) + j;
        int mask = 0;
        if ((hp4 >> j) & 1) {                  // uniform branch (Hp is uniform)
          int a = (quad >> (j * 8)) & 15;
          int dt = (t - tlast) & 15;
          s0 ^= dt ^ a;
          unsigned long long inc0 = 1ULL << ((s0 & 7) * 8);
          c0lo += (s0 < 8) ? inc0 : 0;
          c0hi += (s0 < 8) ? 0 : inc0;
          s1 ^= dt ^ (int)((A1p >> (s0 * 4)) & 15);
          unsigned long long inc1 = 1ULL << ((s1 & 7) * 8);
          c1lo += (s1 < 8) ? inc1 : 0;
          c1hi += (s1 < 8) ? 0 : inc1;
          tlast = t;
          unsigned long long q = (s1 & 8) ? ((s1 & 4) ? P3 : P2)
                                          : ((s1 & 4) ? P1 : P0);
          mask = (int)((q >> ((s1 & 3) * 16)) & 0xFFFF);
        }
        smL[t * 132 + tid] = (unsigned short)mask;
      }
    }
#pragma unroll
    for (int v = 0; v < 8; v++) {
      myc0[v]     = (int)((c0lo >> (v * 8)) & 0xFF);
      myc0[v + 8] = (int)((c0hi >> (v * 8)) & 0xFF);
      myc1[v]     = (int)((c1lo >> (v * 8)) & 0xFF);
      myc1[v + 8] = (int)((c1hi >> (v * 8)) & 0xFF);
    }
  }

  // Reduce counts across the block (threads >= B contribute zeros).
#pragma unroll
  for (int v = 0; v < 16; v++) {
    int a0 = myc0[v], a1 = myc1[v];
#pragma unroll
    for (int off = 32; off > 0; off >>= 1) {
      a0 += __shfl_xor(a0, off);
      a1 += __shfl_xor(a1, off);
    }
    if (lane == 0) { sredc0[wv][v] = a0; sredc1[wv][v] = a1; }
  }
  __syncthreads();
  if (tid < 16) {
    sCnt[tid]      = sredc0[0][tid] + sredc0[1][tid] + sredc0[2][tid] + sredc0[3][tid];
    sCnt[16 + tid] = sredc1[0][tid] + sredc1[1][tid] + sredc1[2][tid] + sredc1[3][tid];
  }
  __syncthreads();

  // Grid-stride output write (spikes raster [b][t][k], then d0, then d1).
  int spikes_n = B * T * n_out;
  int d0_n = n_hid * 16, d1_n = n_out * 16;
  int total = spikes_n + d0_n + d1_n;
  for (int idx = blockIdx.x * 256 + tid; idx < total; idx += (int)gridDim.x * 256) {
    if (idx < spikes_n) {
      int k = idx % n_out;
      int bt = idx / n_out;                // bt = b*T + t
      int b = bt >> 7, t = bt & 127;
      out[idx] = (float)((smL[t * 132 + b] >> k) & 1);
    } else if (idx < spikes_n + d0_n) {
      int i2 = idx - spikes_n;
      int v = i2 & 15;
      out[idx] = ALPHA_F * ((float)v - mem_map0[i2]) * (float)sCnt[v];
    } else {
      int i3 = idx - spikes_n - d0_n;
      int v = i3 & 15;
      out[idx] = ALPHA_F * ((float)v - mem_map1[i3]) * (float)sCnt[16 + v];
    }
  }
}

extern "C" void kernel_launch(void* const* d_in, const int* in_sizes, int n_in,
                              void* d_out, int out_size, void* d_ws, size_t ws_size,
                              hipStream_t stream) {
  const int*   frames     = (const int*)d_in[0];
  const float* v_th0      = (const float*)d_in[3];
  const int*   neuron_id0 = (const int*)d_in[4];
  const float* mem_map0   = (const float*)d_in[5];
  const float* v_th1      = (const float*)d_in[8];
  const float* mem_map1   = (const float*)d_in[10];

  const int n_in_neurons = in_sizes[1];                 // 2312
  const int n_hid        = in_sizes[2];                 // 2048
  const int n_out        = in_sizes[7];                 // 10
  const int B            = 128;
  const int BT           = in_sizes[0] / n_in_neurons;  // 16384
  const int T            = BT / B;                      // 128

  unsigned char* accany = (unsigned char*)d_ws;         // BT bytes, [b][t]
  int* tabs   = (int*)(accany + BT);

  int nblocks = BT / 4;  // one wave per bt
  frames_reduce_kernel<<<nblocks + 1, 256, 0, stream>>>(
      (const iv4*)frames, accany, tabs, v_th0, neuron_id0, mem_map0,
      v_th1, mem_map1, n_in_neurons / 4, n_hid, n_out, nblocks, B, T);
  scan_output_kernel<<<192, 256, 0, stream>>>(
      accany, tabs, mem_map0, mem_map1, (float*)d_out, B, T, n_hid, n_out);
}